// Round 9
// baseline (77.875 us; speedup 1.0000x reference)
//
#include <hip/hip_runtime.h>
#include <hip/hip_bf16.h>
#include <stdint.h>

#define NASSETS 512
#define WINDOW  256
#define NBATCH  32
#define NWORDS  16      // 512 bits / 32
#define BM 128
#define BN 128

typedef __attribute__((ext_vector_type(4))) float floatx4;
typedef __attribute__((ext_vector_type(4))) int   intx4;
typedef __attribute__((ext_vector_type(2))) long  longx2;

// ---- fp32 -> OCP e4m3fn (validated R4-R8: absmax=0) ----
__device__ __forceinline__ unsigned int f2e4m3_manual(float x) {
    union { float f; unsigned u; } c; c.f = x;
    unsigned s = (c.u >> 24) & 0x80u;
    unsigned a = c.u & 0x7FFFFFFFu;
    float af = fabsf(x);
    unsigned code;
    if (af >= 448.f) code = 0x7Eu;
    else if (af < 0.015625f) {
        code = (unsigned)(int)rintf(af * 512.f);
    } else {
        unsigned E = a >> 23;
        unsigned base = ((E - 120u) << 3) | ((a >> 20) & 7u);
        unsigned rem = a & 0xFFFFFu;
        if (rem > 0x80000u || (rem == 0x80000u && (base & 1u))) base++;
        if (base > 0x7Eu) base = 0x7Eu;
        code = base;
    }
    return s | code;
}

__device__ __forceinline__ int pack4fp8(float f0, float f1, float f2, float f3) {
#if defined(__has_builtin) && __has_builtin(__builtin_amdgcn_cvt_pk_fp8_f32)
    int v = 0;
    v = __builtin_amdgcn_cvt_pk_fp8_f32(f0, f1, v, false);
    v = __builtin_amdgcn_cvt_pk_fp8_f32(f2, f3, v, true);
    return v;
#else
    return (int)(f2e4m3_manual(f0) | (f2e4m3_manual(f1) << 8) |
                 (f2e4m3_manual(f2) << 16) | (f2e4m3_manual(f3) << 24));
#endif
}

// async global->LDS, 16B/lane; LDS dst wave-uniform base + lane*16
__device__ __forceinline__ void gload16(const void* gp, void* lp) {
    __builtin_amdgcn_global_load_lds(
        (const __attribute__((address_space(1))) void*)(uintptr_t)gp,
        (__attribute__((address_space(3))) void*)(unsigned int)(uintptr_t)lp,
        16, 0, 0);
}

// Kernel 1 (v5): float4-coalesced read -> LDS raw tile -> R8-proven stats/pack path.
// grid (16 asset-groups of 32, 32 batches), block 512 (8 waves).
// Phase A: 4 float4 loads/thread -> raw[w][n] (256 x 32 fp32, 32 KB).
// Phase B: thread (a=t&31, wc=t>>5) reads its 16-float column chunk from LDS,
// stats via LDS reduce, fp8 pack into out-tile (aliases raw[0..8K), safe: all
// raw reads precede sync1). Phase C: coalesced transposed writeout.
// Xt row layout IDENTICAL to R5-R8 (4 slabs; slot q of slab s = k[s*64+q*8..+7]
// ++ k[s*64+32+q*8..+7], written in logical order to global).
__global__ __launch_bounds__(512)
void normalize_kernel(const float* __restrict__ ret, char* __restrict__ Xt) {
    __shared__ __align__(16) char raw[32768];   // A: raw fp32 tile; C: out tile (first 8 KB)
    __shared__ float sred[512];
    __shared__ float ssred[512];
    __shared__ float smean[32];
    __shared__ float sinv[32];

    const int t  = threadIdx.x;
    const int g  = blockIdx.x;
    const int b  = blockIdx.y;
    const int n0 = g * 32;

    const float* gbase = ret + (size_t)b * WINDOW * NASSETS + n0;
    float* rawf = (float*)raw;

    // Phase A: coalesced float4 loads (16 lanes x 4 rows per wave-instr)
#pragma unroll
    for (int i = 0; i < 4; ++i) {
        int f  = i * 512 + t;
        int w  = f >> 3;          // 0..255
        int nq = f & 7;           // float4 within 32-asset row
        floatx4 v = *(const floatx4*)(gbase + (size_t)w * NASSETS + nq * 4);
        *(floatx4*)(raw + w * 128 + nq * 16) = v;
    }
    __syncthreads();

    // Phase B: column stats + fp8 pack (R8-validated math, source = LDS)
    const int a  = t & 31;
    const int wc = t >> 5;                 // 0..15, 16 w's each
    float x[16];
    float s1 = 0.f, s2 = 0.f;
#pragma unroll
    for (int k = 0; k < 16; ++k) {
        x[k] = rawf[(wc * 16 + k) * 32 + a];
        s1 += x[k];
        s2 += x[k] * x[k];
    }
    sred[wc * 32 + a]  = s1;
    ssred[wc * 32 + a] = s2;
    __syncthreads();   // sync1: all raw reads + sred stores done

    if (t < 32) {
        float S = 0.f, S2 = 0.f;
#pragma unroll
        for (int c = 0; c < 16; ++c) { S += sred[c * 32 + t]; S2 += ssred[c * 32 + t]; }
        float mean = S / (float)WINDOW;
        float var  = (S2 - (float)WINDOW * mean * mean) / (float)(WINDOW - 1);
        if (var < 0.f) var = 0.f;
        float stdv = sqrtf(var) + 1e-8f;   // ref: std(ddof=1) + 1e-8
        smean[t] = mean;
        sinv[t]  = 1.0f / stdv;
    }
    __syncthreads();   // sync2: stats visible; raw tile dead -> reuse as out tile

    const float mn = smean[a];
    const float iv = sinv[a];

    int pk[4];
#pragma unroll
    for (int j = 0; j < 4; ++j)
        pk[j] = pack4fp8((x[4*j+0] - mn) * iv, (x[4*j+1] - mn) * iv,
                         (x[4*j+2] - mn) * iv, (x[4*j+3] - mn) * iv);

    // thread's 16 w = w[wc*16..+15]: slab s=wc>>2; half h8=(wc&2)?8:0; qbase=(wc&1)*2
    char* rowp = raw + a * 256;            // out tile: 32 rows x 256 B
    const int s     = wc >> 2;
    const int h8    = (wc & 2) ? 8 : 0;
    const int qbase = (wc & 1) * 2;
#pragma unroll
    for (int q = 0; q < 2; ++q) {
        unsigned long long piece = (unsigned)pk[2*q] |
                                   ((unsigned long long)(unsigned)pk[2*q+1] << 32);
        int L = s * 4 + qbase + q;
        *(unsigned long long*)(rowp + ((L ^ (a & 15)) * 16) + h8) = piece;
    }
    __syncthreads();   // sync3: out tile complete

    // Phase C: writeout, 512 16B segs; wave covers 4 rows = 1 KB contiguous
    char* orow = Xt + ((size_t)b * NASSETS + n0) * WINDOW;
    {
        int r  = t >> 4;                   // 0..31
        int sl = t & 15;
        intx4 v = *(const intx4*)(raw + r * 256 + ((sl ^ (r & 15)) * 16));
        *(intx4*)(orow + r * WINDOW + sl * 16) = v;
    }
}

// Kernel 2 (v6): 128x128 corr tile, fp8 MFMA, FULL-K LDS staging (single barrier,
// 128 MFMA/wave between barriers). grid (4 jt, 4 it, 32 b) = 512 blocks, block 256.
// LDS rows 256 B (full K); phys 16B slot p of row r holds logical slot p^(r&15).
__global__ __launch_bounds__(256)
void corr_adj_kernel(const char* __restrict__ Xt, unsigned int* __restrict__ adj) {
    __shared__ __align__(16) char lsA[BM * 256];   // 32 KB
    __shared__ __align__(16) char lsB[BN * 256];   // 32 KB

    const int t    = threadIdx.x;
    const int lane = t & 63;
    const int wave = t >> 6;
    const int wi   = wave >> 1, wj = wave & 1;
    const int b  = blockIdx.z;
    const int i0 = blockIdx.y * BM;
    const int j0 = blockIdx.x * BN;

    const char* base = Xt + (size_t)b * NASSETS * WINDOW;

    const int m  = lane & 15;
    const int kq = lane >> 4;

    // staging: one instr = 4 rows x 256 B; lane l -> row +(l>>4), phys slot l&15,
    // logical slot (l&15) ^ (row&15)
    const int rl = lane >> 4;
    const int pl = lane & 15;

    // issue all 16 staging instrs (wave stages rows [wave*32, wave*32+32) of both tiles)
#pragma unroll
    for (int c = 0; c < 8; ++c) {
        int r0 = wave * 32 + c * 4;
        int rr = (r0 & 15) + rl;                    // (row & 15), no wrap: r0%16 in {0,4,8,12}
        int gs = (pl ^ rr) * 16;
        const char* gA = base + (size_t)(i0 + r0 + rl) * WINDOW + gs;
        const char* gB = base + (size_t)(j0 + r0 + rl) * WINDOW + gs;
        gload16(gA, (char*)lsA + r0 * 256);
        gload16(gB, (char*)lsB + r0 * 256);
    }
    __syncthreads();   // vmcnt drained -> full-K tiles visible

    floatx4 acc[4][4] = {};

#pragma unroll
    for (int s = 0; s < 4; ++s) {
        longx2 af[4], bf[4];
#pragma unroll
        for (int mi = 0; mi < 4; ++mi) {
            int r = wi * 64 + mi * 16 + m;
            af[mi] = *(const longx2*)(lsA + r * 256 + (((s * 4 + kq) ^ (r & 15)) * 16));
        }
#pragma unroll
        for (int nj = 0; nj < 4; ++nj) {
            int r = wj * 64 + nj * 16 + m;
            bf[nj] = *(const longx2*)(lsB + r * 256 + (((s * 4 + kq) ^ (r & 15)) * 16));
        }
#pragma unroll
        for (int mi = 0; mi < 4; ++mi)
#pragma unroll
            for (int nj = 0; nj < 4; ++nj) {
                acc[mi][nj] = __builtin_amdgcn_mfma_f32_16x16x32_fp8_fp8(
                    af[mi].x, bf[nj].x, acc[mi][nj], 0, 0, 0);
                acc[mi][nj] = __builtin_amdgcn_mfma_f32_16x16x32_fp8_fp8(
                    af[mi].y, bf[nj].y, acc[mi][nj], 0, 0, 0);
            }
    }

    // Ballot bit-pack epilogue (validated R2-R8). C/D: col=lane&15, row=(lane>>4)*4+r.
    const float T[3] = {0.3f * (float)WINDOW, 0.5f * (float)WINDOW, 0.7f * (float)WINDOW};
    unsigned int wout[3][2] = {{0u,0u},{0u,0u},{0u,0u}};
    const int qp = (lane >> 2) & 3;
#pragma unroll
    for (int mi = 0; mi < 4; ++mi) {
#pragma unroll
        for (int r = 0; r < 4; ++r) {
            bool act = ((lane >> 4) == mi) && ((lane & 3) == r);
#pragma unroll
            for (int th = 0; th < 3; ++th) {
                unsigned long long b0 = __ballot(fabsf(acc[mi][0][r]) > T[th]);
                unsigned long long b1 = __ballot(fabsf(acc[mi][1][r]) > T[th]);
                unsigned long long b2 = __ballot(fabsf(acc[mi][2][r]) > T[th]);
                unsigned long long b3 = __ballot(fabsf(acc[mi][3][r]) > T[th]);
                if (act) {
                    wout[th][0] = ((unsigned)(b0 >> (qp * 16)) & 0xFFFFu)
                                | (((unsigned)(b1 >> (qp * 16)) & 0xFFFFu) << 16);
                    wout[th][1] = ((unsigned)(b2 >> (qp * 16)) & 0xFFFFu)
                                | (((unsigned)(b3 >> (qp * 16)) & 0xFFFFu) << 16);
                }
            }
        }
    }

    const int grow    = i0 + wi * 64 + lane;
    const int colbase = j0 + wj * 64;
    unsigned int dd = (unsigned int)(grow - colbase);
    if (dd < 64u) {
        unsigned int m0 = (dd < 32u) ? ~(1u << dd) : 0xFFFFFFFFu;
        unsigned int m1 = (dd >= 32u) ? ~(1u << (dd - 32u)) : 0xFFFFFFFFu;
#pragma unroll
        for (int th = 0; th < 3; ++th) { wout[th][0] &= m0; wout[th][1] &= m1; }
    }
    const int wb = colbase >> 5;
    const size_t stride_t = (size_t)NBATCH * NASSETS * NWORDS;
    size_t rb = ((size_t)b * NASSETS + grow) * NWORDS + wb;
#pragma unroll
    for (int th = 0; th < 3; ++th) {
        adj[rb + th * stride_t]     = wout[th][0];
        adj[rb + th * stride_t + 1] = wout[th][1];
    }
}

// Kernel 3 (R5-validated, unchanged): CC (min-label + pointer jumping) + edges.
__global__ __launch_bounds__(512)
void betti_kernel(const unsigned int* __restrict__ adj, float* __restrict__ out) {
    __shared__ int lab[NASSETS];
    __shared__ int changed;
    __shared__ int red[8];

    int th = blockIdx.x;
    int b  = blockIdx.y;
    int i  = threadIdx.x;
    int lane = i & 63, wv = i >> 6;

    const unsigned int* rowp =
        adj + (((size_t)th * NBATCH + b) * NASSETS + i) * NWORDS;
    unsigned int row[NWORDS];
    int deg = 0;
#pragma unroll
    for (int w = 0; w < NWORDS; ++w) {
        row[w] = rowp[w];
        deg += __popc(row[w]);
    }

    int v = deg;
#pragma unroll
    for (int off = 32; off > 0; off >>= 1) v += __shfl_down(v, off);
    if (lane == 0) red[wv] = v;
    lab[i] = i;
    __syncthreads();
    int total_deg = 0;
    if (i == 0)
        for (int k = 0; k < 8; ++k) total_deg += red[k];

    for (;;) {
        __syncthreads();
        if (i == 0) changed = 0;
        __syncthreads();
        int mlab = lab[i];
#pragma unroll
        for (int w = 0; w < NWORDS; ++w) {
            unsigned int bits = row[w];
            int basej = w * 32;
            while (bits) {
                int j = basej + __builtin_ctz(bits);
                bits &= bits - 1;
                int lj = lab[j];
                if (lj < mlab) mlab = lj;
            }
        }
        int lm = lab[mlab];
        if (lm < mlab) mlab = lm;
        __syncthreads();
        if (mlab < lab[i]) { lab[i] = mlab; changed = 1; }
        __syncthreads();
        if (!changed) break;
    }

    int isrep = (lab[i] == i) ? 1 : 0;
#pragma unroll
    for (int off = 32; off > 0; off >>= 1) isrep += __shfl_down(isrep, off);
    if (lane == 0) red[wv] = isrep;
    __syncthreads();
    if (i == 0) {
        int comps = 0;
        for (int k = 0; k < 8; ++k) comps += red[k];
        float compf = (float)comps;
        float edges = (float)total_deg * 0.5f;
        out[b * 6 + th * 2 + 0] = compf / (float)NASSETS;
        out[b * 6 + th * 2 + 1] = fmaxf(0.0f, edges - (float)NASSETS + compf) / (float)NASSETS;
    }
}

extern "C" void kernel_launch(void* const* d_in, const int* in_sizes, int n_in,
                              void* d_out, int out_size, void* d_ws, size_t ws_size,
                              hipStream_t stream) {
    const float* ret = (const float*)d_in[0];
    float* out = (float*)d_out;
    char* ws = (char*)d_ws;

    char* Xt = ws;                                                    // 4 MB fp8
    unsigned int* adj =
        (unsigned int*)(ws + (size_t)NBATCH * NASSETS * WINDOW);      // 3 MB

    dim3 g1(NASSETS / 32, NBATCH);
    normalize_kernel<<<g1, 512, 0, stream>>>(ret, Xt);

    dim3 g2(NASSETS / BN, NASSETS / BM, NBATCH);
    corr_adj_kernel<<<g2, 256, 0, stream>>>(Xt, adj);

    dim3 g3(3, NBATCH);
    betti_kernel<<<g3, 512, 0, stream>>>(adj, out);
}